// Round 4
// baseline (462.887 us; speedup 1.0000x reference)
//
#include <hip/hip_runtime.h>
#include <math.h>

#define N_NODES 200000
#define NGRAPH  512
#define HID     256
#define NTILES  (N_NODES / 16)        // 12500
#define NBLK    512
#define NWAVE   (NBLK * 4)            // 2048 waves
#define TPW     (NTILES / NWAVE)      // 6 base tiles/wave
#define TREM    (NTILES - NWAVE * TPW)  // 212 waves get one extra

typedef __attribute__((ext_vector_type(8))) short s16x8;
typedef __attribute__((ext_vector_type(4))) float f32x4;

__device__ __forceinline__ unsigned int pack2_bf16_rne(float a, float b) {
  unsigned int ua = __float_as_uint(a), ub = __float_as_uint(b);
  unsigned int ra = (ua + 0x7fffu + ((ua >> 16) & 1u)) >> 16;
  unsigned int rb = (ub + 0x7fffu + ((ub >> 16) & 1u)) & 0xffff0000u;
  return ra | rb;
}
__device__ __forceinline__ int lower_bound_batch(const int* __restrict__ batch, int target) {
  int lo = 0, hi = N_NODES;
  while (lo < hi) { int mid = (lo + hi) >> 1; if (batch[mid] < target) lo = mid + 1; else hi = mid; }
  return lo;
}
// order-preserving float->uint key for atomicMax (all finite floats)
__device__ __forceinline__ unsigned fkey(float f) {
  unsigned u = __float_as_uint(f);
  return (u >> 31) ? ~u : (u | 0x80000000u);
}

// ---------------------------------------------------------------------------
// Fused gate+pool, single HBM pass over x.
//  - 512 blocks x 256thr; wave-private SINGLE 16-row LDS buffer (16 KB/wave,
//    64 KB/block -> 2 blocks/CU -> 2 waves/SIMD: bubbles overlap)
//  - next tile prefetched into 16 float4 REGS before compute (T14: HBM
//    latency hides under MFMA+pool), then ds_write with write-side swizzle
//    (rule 21: reg-staging allows swizzle both sides; reads unchanged)
//  - batch via uniform scalar loads (s_load, no LDS round-trip); fast path
//    when tile is single-segment (96% of tiles); ei[16] extracted once via
//    constant-lane shfl (readlane) -> pool loop is pure ds_read_b128 + VALU
//  - all waitcnts compiler-managed (no asm); partials flushed with atomics
// ---------------------------------------------------------------------------
__global__ __launch_bounds__(256, 2) void fused_gate_pool(
    const float* __restrict__ x, const int* __restrict__ batch,
    const float* __restrict__ w1, const float* __restrict__ b1,
    const float* __restrict__ w2, const float* __restrict__ b2,
    float* __restrict__ gsum, unsigned* __restrict__ gmx,
    float* __restrict__ gat, float* __restrict__ gden)
{
  struct Buf { float xrow[16][256]; };
  __shared__ __align__(16) Buf stg[4];   // 65,536 B

  const int tid = threadIdx.x;
  const int w = tid >> 6, lane = tid & 63, q = lane >> 4, c = lane & 15;
  const int gw = blockIdx.x * 4 + w;

  const int t0   = gw * TPW + (gw < TREM ? gw : TREM);
  const int tend = t0 + TPW + (gw < TREM ? 1 : 0);

  // B fragments in registers: bh[nt][kt] = bf16 w1[k = kt*32+q*8+j][n = nt*16+c]
  s16x8 bh[4][8];
#pragma unroll
  for (int nt = 0; nt < 4; ++nt) {
#pragma unroll
    for (int kt = 0; kt < 8; ++kt) {
      float f[8];
#pragma unroll
      for (int j = 0; j < 8; ++j)
        f[j] = w1[(size_t)(kt * 32 + q * 8 + j) * 64 + nt * 16 + c];
      union { s16x8 v; unsigned u[4]; } tmp;
      tmp.u[0] = pack2_bf16_rne(f[0], f[1]);
      tmp.u[1] = pack2_bf16_rne(f[2], f[3]);
      tmp.u[2] = pack2_bf16_rne(f[4], f[5]);
      tmp.u[3] = pack2_bf16_rne(f[6], f[7]);
      bh[nt][kt] = tmp.v;
    }
  }
  float b1v[4], w2v[4];
#pragma unroll
  for (int nt = 0; nt < 4; ++nt) { b1v[nt] = b1[nt * 16 + c]; w2v[nt] = w2[nt * 16 + c]; }
  const float b2v = b2[0];

  const int csw = (c & 7) << 4;

  f32x4 sum = (f32x4){0.f, 0.f, 0.f, 0.f};
  f32x4 at  = (f32x4){0.f, 0.f, 0.f, 0.f};
  f32x4 mx  = (f32x4){-INFINITY, -INFINITY, -INFINITY, -INFINITY};
  float den = 0.f;
  int curseg = -1;

  float4 pf[16];
  auto LOADR = [&](int t) {
    const float* rowbase = x + (size_t)t * 4096 + lane * 4;
#pragma unroll
    for (int r = 0; r < 16; ++r)
      pf[r] = *(const float4*)(rowbase + r * 256);
  };
  auto WRITE = [&]() {
#pragma unroll
    for (int r = 0; r < 16; ++r)
      *(float4*)((char*)&stg[w].xrow[r][0] + ((lane * 16) ^ ((r & 7) << 4))) = pf[r];
  };
  auto FLUSH = [&](int seg) {
    float* sp = gsum + (size_t)seg * 256 + lane * 4;
    float* ap = gat  + (size_t)seg * 256 + lane * 4;
    unsigned* mp = gmx + (size_t)seg * 256 + lane * 4;
#pragma unroll
    for (int j = 0; j < 4; ++j) {
      atomicAdd(&sp[j], sum[j]);
      atomicAdd(&ap[j], at[j]);
      atomicMax(&mp[j], fkey(mx[j]));
    }
    if (lane == 0) atomicAdd(&gden[seg], den);
  };
  auto RESET = [&]() {
    sum = (f32x4){0.f, 0.f, 0.f, 0.f};
    at  = (f32x4){0.f, 0.f, 0.f, 0.f};
    mx  = (f32x4){-INFINITY, -INFINITY, -INFINITY, -INFINITY};
    den = 0.f;
  };

  LOADR(t0);

  for (int t = t0; t < tend; ++t) {
    WRITE();                          // compiler waits vmcnt on pf uses
    if (t + 1 < tend) LOADR(t + 1);   // prefetch in flight during compute

    // ---- A fragments from LDS (fp32 -> bf16 pack), row = c, swizzled ----
    const char* rb = (const char*)&stg[w].xrow[c][0];
    union { s16x8 v; unsigned u[4]; } ah[8];
#pragma unroll
    for (int kt = 0; kt < 8; ++kt) {
      const int base = kt * 128 + q * 32;
      float4 t0v = *(const float4*)(rb + ((base)      ^ csw));
      float4 t1v = *(const float4*)(rb + ((base + 16) ^ csw));
      ah[kt].u[0] = pack2_bf16_rne(t0v.x, t0v.y);
      ah[kt].u[1] = pack2_bf16_rne(t0v.z, t0v.w);
      ah[kt].u[2] = pack2_bf16_rne(t1v.x, t1v.y);
      ah[kt].u[3] = pack2_bf16_rne(t1v.z, t1v.w);
    }

    f32x4 acc[4];
#pragma unroll
    for (int nt = 0; nt < 4; ++nt) acc[nt] = (f32x4){0.f, 0.f, 0.f, 0.f};
#pragma unroll
    for (int kt = 0; kt < 8; ++kt) {
#pragma unroll
      for (int nt = 0; nt < 4; ++nt)
        acc[nt] = __builtin_amdgcn_mfma_f32_16x16x32_bf16(ah[kt].v, bh[nt][kt], acc[nt], 0, 0, 0);
    }

    // ---- gate epilogue: D[row=4q+r][col=nt*16+c]; butterfly over c ----
    float er[4];
#pragma unroll
    for (int r = 0; r < 4; ++r) {
      float sv = 0.f;
#pragma unroll
      for (int nt = 0; nt < 4; ++nt) {
        float h = acc[nt][r] + b1v[nt];
        h = h > 0.f ? h : 0.f;
        sv += h * w2v[nt];
      }
      sv += __shfl_xor(sv, 1, 64);
      sv += __shfl_xor(sv, 2, 64);
      sv += __shfl_xor(sv, 4, 64);
      sv += __shfl_xor(sv, 8, 64);
      er[r] = __expf(sv + b2v);   // shift-free softmax numerator (|g|<~5)
    }
    // all 16 row weights into registers (constant-lane shfl -> readlane)
    float ei[16];
#pragma unroll
    for (int i = 0; i < 16; ++i) ei[i] = __shfl(er[i & 3], (i >> 2) << 4, 64);

    // ---- pool accumulation: lane owns cols lane*4..+3 ----
    const int r0t = t << 4;
    const int sg0  = batch[r0t];        // uniform -> s_load
    const int sg15 = batch[r0t + 15];   // uniform -> s_load
    if (sg0 == sg15) {                  // fast path: single-segment tile (96%)
      if (sg0 != curseg) {
        if (curseg >= 0) FLUSH(curseg);
        RESET();
        curseg = sg0;
      }
#pragma unroll
      for (int i = 0; i < 16; ++i) {
        const float4 v = *(const float4*)((const char*)&stg[w].xrow[i][0] +
                                          ((lane * 16) ^ ((i & 7) << 4)));
        den += ei[i];
        sum[0] += v.x; sum[1] += v.y; sum[2] += v.z; sum[3] += v.w;
        mx[0] = fmaxf(mx[0], v.x); mx[1] = fmaxf(mx[1], v.y);
        mx[2] = fmaxf(mx[2], v.z); mx[3] = fmaxf(mx[3], v.w);
        at[0] = fmaf(ei[i], v.x, at[0]); at[1] = fmaf(ei[i], v.y, at[1]);
        at[2] = fmaf(ei[i], v.z, at[2]); at[3] = fmaf(ei[i], v.w, at[3]);
      }
    } else {                            // boundary tile: per-row segment check
#pragma unroll
      for (int i = 0; i < 16; ++i) {
        const int sg = batch[r0t + i];  // uniform -> s_load
        if (sg != curseg) {
          if (curseg >= 0) FLUSH(curseg);
          RESET();
          curseg = sg;
        }
        const float4 v = *(const float4*)((const char*)&stg[w].xrow[i][0] +
                                          ((lane * 16) ^ ((i & 7) << 4)));
        den += ei[i];
        sum[0] += v.x; sum[1] += v.y; sum[2] += v.z; sum[3] += v.w;
        mx[0] = fmaxf(mx[0], v.x); mx[1] = fmaxf(mx[1], v.y);
        mx[2] = fmaxf(mx[2], v.z); mx[3] = fmaxf(mx[3], v.w);
        at[0] = fmaf(ei[i], v.x, at[0]); at[1] = fmaf(ei[i], v.y, at[1]);
        at[2] = fmaf(ei[i], v.z, at[2]); at[3] = fmaf(ei[i], v.w, at[3]);
      }
    }
  }
  if (curseg >= 0) FLUSH(curseg);
}

// ---------------------------------------------------------------------------
// Finalize + head: z = {sum/cnt, decode(max), attn/den}; y = z@wp+bp; LN.
// ---------------------------------------------------------------------------
__global__ __launch_bounds__(256) void head_ln(
    const float* __restrict__ gsum, const unsigned* __restrict__ gmx,
    const float* __restrict__ gat, const float* __restrict__ gden,
    const int* __restrict__ batch, const float* __restrict__ wp,
    const float* __restrict__ bp, const float* __restrict__ gam,
    const float* __restrict__ bet, float* __restrict__ out)
{
  const int g = blockIdx.x;
  const int tid = threadIdx.x;
  const int w = tid >> 6, lane = tid & 63;
  __shared__ int sb[2];
  __shared__ float z[768];
  __shared__ __align__(16) float part[4][256];
  __shared__ float red[256];

  if (tid < 2) sb[tid] = lower_bound_batch(batch, g + tid);
  __syncthreads();
  const float cnt = (float)(sb[1] - sb[0]);

  {
    const float s = gsum[(size_t)g * 256 + tid];
    const unsigned k = gmx[(size_t)g * 256 + tid];
    const unsigned u = (k & 0x80000000u) ? (k ^ 0x80000000u) : ~k;
    const float a = gat[(size_t)g * 256 + tid];
    const float den = gden[g];
    z[tid]       = (cnt > 0.f) ? s / cnt : 0.f;
    z[256 + tid] = (cnt > 0.f) ? __uint_as_float(u) : 0.f;
    z[512 + tid] = a / fmaxf(den, 1e-16f);
  }
  __syncthreads();

  f32x4 acc = (f32x4){0.f, 0.f, 0.f, 0.f};
  const float4* wp4 = (const float4*)wp;  // wp[k*256 + lane*4] = wp4[k*64 + lane]
  const int k0 = w * 192;
#pragma unroll 8
  for (int k = k0; k < k0 + 192; ++k) {
    float4 wv = wp4[(size_t)k * 64 + lane];
    float zk = z[k];
    acc[0] = fmaf(zk, wv.x, acc[0]);
    acc[1] = fmaf(zk, wv.y, acc[1]);
    acc[2] = fmaf(zk, wv.z, acc[2]);
    acc[3] = fmaf(zk, wv.w, acc[3]);
  }
  *(f32x4*)&part[w][lane * 4] = acc;
  __syncthreads();

  const int t = tid;
  float y = bp[t] + part[0][t] + part[1][t] + part[2][t] + part[3][t];

  red[t] = y;
  __syncthreads();
  for (int wd = 128; wd > 0; wd >>= 1) {
    if (t < wd) red[t] += red[t + wd];
    __syncthreads();
  }
  const float mu = red[0] * (1.f / 256.f);
  __syncthreads();
  float d = y - mu;
  red[t] = d * d;
  __syncthreads();
  for (int wd = 128; wd > 0; wd >>= 1) {
    if (t < wd) red[t] += red[t + wd];
    __syncthreads();
  }
  const float var = red[0] * (1.f / 256.f);
  const float is = rsqrtf(var + 1e-5f);
  out[(size_t)g * 256 + t] = fmaf(d * is, gam[t], bet[t]);
}

// ---------------------------------------------------------------------------
extern "C" void kernel_launch(void* const* d_in, const int* in_sizes, int n_in,
                              void* d_out, int out_size, void* d_ws, size_t ws_size,
                              hipStream_t stream) {
  const float* x   = (const float*)d_in[0];
  const int*   bat = (const int*)d_in[1];
  const float* w1  = (const float*)d_in[2];
  const float* b1  = (const float*)d_in[3];
  const float* w2  = (const float*)d_in[4];
  const float* b2  = (const float*)d_in[5];
  const float* wp  = (const float*)d_in[6];
  const float* bp  = (const float*)d_in[7];
  const float* gam = (const float*)d_in[8];
  const float* bet = (const float*)d_in[9];
  float* out = (float*)d_out;

  // ws: gsum[512*256] | gmx[512*256] | gat[512*256] | gden[512]
  float* gsum   = (float*)d_ws;
  unsigned* gmx = (unsigned*)(gsum + (size_t)NGRAPH * 256);
  float* gat    = (float*)(gmx + (size_t)NGRAPH * 256);
  float* gden   = gat + (size_t)NGRAPH * 256;
  const size_t zbytes = ((size_t)NGRAPH * 256 * 3 + NGRAPH) * 4;

  hipMemsetAsync(d_ws, 0, zbytes, stream);
  hipLaunchKernelGGL(fused_gate_pool, dim3(NBLK), dim3(256), 0, stream,
                     x, bat, w1, b1, w2, b2, gsum, gmx, gat, gden);
  hipLaunchKernelGGL(head_ln, dim3(NGRAPH), dim3(256), 0, stream,
                     gsum, gmx, gat, gden, bat, wp, bp, gam, bet, out);
}

// Round 6
// 346.897 us; speedup vs baseline: 1.3344x; 1.3344x over previous
//
#include <hip/hip_runtime.h>
#include <math.h>

#define N_NODES 200000
#define NGRAPH  512
#define HID     256
#define NTILES  (N_NODES / 16)        // 12500
#define NBLK    1024
#define NWAVE   (NBLK * 4)            // 4096 waves
#define TPW     (NTILES / NWAVE)      // 3 base tiles/wave
#define TREM    (NTILES - NWAVE * TPW)  // 212 waves get one extra

typedef __attribute__((ext_vector_type(8))) short s16x8;
typedef __attribute__((ext_vector_type(4))) float f32x4;

__device__ __forceinline__ unsigned short f2bf_rne(float f) {
  unsigned int u = __float_as_uint(f);
  return (unsigned short)((u + 0x7fffu + ((u >> 16) & 1u)) >> 16);
}
__device__ __forceinline__ unsigned int pack2_bf16_rne(float a, float b) {
  unsigned int ua = __float_as_uint(a), ub = __float_as_uint(b);
  unsigned int ra = (ua + 0x7fffu + ((ua >> 16) & 1u)) >> 16;
  unsigned int rb = (ub + 0x7fffu + ((ub >> 16) & 1u)) & 0xffff0000u;
  return ra | rb;
}
__device__ __forceinline__ int lower_bound_batch(const int* __restrict__ batch, int target) {
  int lo = 0, hi = N_NODES;
  while (lo < hi) { int mid = (lo + hi) >> 1; if (batch[mid] < target) lo = mid + 1; else hi = mid; }
  return lo;
}
// order-preserving float->uint key for atomicMax (all finite floats)
__device__ __forceinline__ unsigned fkey(float f) {
  unsigned u = __float_as_uint(f);
  return (u >> 31) ? ~u : (u | 0x80000000u);
}

// ---------------------------------------------------------------------------
// Fused gate+pool, single HBM pass over x. Register-budgeted (R4 post-mortem:
// bh-in-regs 128 + pf 64 spilled 250 MB to scratch):
//  - w1T bf16 in SHARED LDS (33 KB, loaded once/block)  -> frees 128 VGPRs
//  - tile reg-staged (pf[16], lane owns cols 4L..4L+3), then packed to a
//    wave-private bf16 LDS buffer (8 KB/wave) for the MFMA A-fragments
//  - LDS total 66.5 KB -> 2 blocks/CU -> 2 waves/SIMD (2x R3/R4)
//  - XOR swizzle byte^((row&7)<<4) on BOTH ds_write and ds_read (rule 21:
//    reg-staged write allows it); without it the 512 B row stride is a
//    16-way bank conflict on the A-frag reads
//  - pool accumulates straight from pf registers (fp32): no LDS round-trip
//  - batch via uniform s_loads; single-segment fast path; no barriers in loop
// ---------------------------------------------------------------------------
__global__ __launch_bounds__(256, 2) void fused_gate_pool(
    const float* __restrict__ x, const int* __restrict__ batch,
    const float* __restrict__ w1, const float* __restrict__ b1,
    const float* __restrict__ w2, const float* __restrict__ b2,
    float* __restrict__ gsum, unsigned* __restrict__ gmx,
    float* __restrict__ gat, float* __restrict__ gden)
{
  __shared__ __align__(16) short w1T[64 * 264];            // 33,792 B
  __shared__ __align__(16) unsigned short stg[4][16][256]; // 32,768 B

  const int tid = threadIdx.x;
  const int w = tid >> 6, lane = tid & 63, q = lane >> 4, c = lane & 15;
  const int gw = blockIdx.x * 4 + w;

  const int t0   = gw * TPW + (gw < TREM ? gw : TREM);
  const int tend = t0 + TPW + (gw < TREM ? 1 : 0);

  for (int i = tid; i < 256 * 64; i += 256) {  // i = k*64 + n, coalesced
    int k = i >> 6, n = i & 63;
    w1T[n * 264 + k] = (short)f2bf_rne(w1[i]);
  }
  __syncthreads();   // the only barrier in the kernel

  float b1v[4], w2v[4];
#pragma unroll
  for (int nt = 0; nt < 4; ++nt) { b1v[nt] = b1[nt * 16 + c]; w2v[nt] = w2[nt * 16 + c]; }
  const float b2v = b2[0];

  f32x4 sum = (f32x4){0.f, 0.f, 0.f, 0.f};
  f32x4 at  = (f32x4){0.f, 0.f, 0.f, 0.f};
  f32x4 mx  = (f32x4){-INFINITY, -INFINITY, -INFINITY, -INFINITY};
  float den = 0.f;
  int curseg = -1;

  auto FLUSH = [&](int seg) {
    float* sp = gsum + (size_t)seg * 256 + lane * 4;
    float* ap = gat  + (size_t)seg * 256 + lane * 4;
    unsigned* mp = gmx + (size_t)seg * 256 + lane * 4;
#pragma unroll
    for (int j = 0; j < 4; ++j) {
      atomicAdd(&sp[j], sum[j]);
      atomicAdd(&ap[j], at[j]);
      atomicMax(&mp[j], fkey(mx[j]));
    }
    if (lane == 0) atomicAdd(&gden[seg], den);
  };
  auto RESET = [&]() {
    sum = (f32x4){0.f, 0.f, 0.f, 0.f};
    at  = (f32x4){0.f, 0.f, 0.f, 0.f};
    mx  = (f32x4){-INFINITY, -INFINITY, -INFINITY, -INFINITY};
    den = 0.f;
  };

  char* swave = (char*)&stg[w][0][0];
  const char* rb = swave + c * 512;        // A-frag base: row c
  const int ck = (c & 7) << 4;             // read-side swizzle key

  for (int t = t0; t < tend; ++t) {
    // ---- load tile into regs: lane owns cols 4*lane..+3 of 16 rows ----
    float4 pf[16];
    const float* rowbase = x + (size_t)t * 4096 + lane * 4;
#pragma unroll
    for (int r = 0; r < 16; ++r) pf[r] = *(const float4*)(rowbase + r * 256);

    // ---- pack & stage bf16 rows (write-side swizzle, key (r&7)) ----
#pragma unroll
    for (int r = 0; r < 16; ++r) {
      unsigned lo = pack2_bf16_rne(pf[r].x, pf[r].y);
      unsigned hi = pack2_bf16_rne(pf[r].z, pf[r].w);
      char* dst = swave + r * 512 + ((lane * 8) ^ ((r & 7) << 4));
      *(uint2*)dst = make_uint2(lo, hi);   // ds_write_b64, 2-way (free)
    }

    // ---- MFMA: A row c from LDS (swizzled), B from shared w1T ----
    f32x4 acc[4];
#pragma unroll
    for (int nt = 0; nt < 4; ++nt) acc[nt] = (f32x4){0.f, 0.f, 0.f, 0.f};
#pragma unroll
    for (int kt = 0; kt < 8; ++kt) {
      s16x8 av = *(const s16x8*)(rb + ((kt * 64 + q * 16) ^ ck));
#pragma unroll
      for (int nt = 0; nt < 4; ++nt) {
        s16x8 bv = *(const s16x8*)&w1T[(nt * 16 + c) * 264 + kt * 32 + q * 8];
        acc[nt] = __builtin_amdgcn_mfma_f32_16x16x32_bf16(av, bv, acc[nt], 0, 0, 0);
      }
    }

    // ---- gate epilogue: D[row=4q+r][col=nt*16+c]; butterfly over c ----
    float er[4];
#pragma unroll
    for (int r = 0; r < 4; ++r) {
      float sv = 0.f;
#pragma unroll
      for (int nt = 0; nt < 4; ++nt) {
        float h = acc[nt][r] + b1v[nt];
        h = h > 0.f ? h : 0.f;
        sv += h * w2v[nt];
      }
      sv += __shfl_xor(sv, 1, 64);
      sv += __shfl_xor(sv, 2, 64);
      sv += __shfl_xor(sv, 4, 64);
      sv += __shfl_xor(sv, 8, 64);
      er[r] = __expf(sv + b2v);   // shift-free softmax numerator (|g|<~5)
    }

    // ---- pool straight from pf registers (fp32) ----
    const int r0t = t << 4;
    const int sg0  = batch[r0t];        // uniform -> s_load
    const int sg15 = batch[r0t + 15];   // uniform -> s_load
    if (sg0 != curseg) {
      if (curseg >= 0) FLUSH(curseg);
      RESET();
      curseg = sg0;
    }
    if (sg0 == sg15) {                  // fast path: single-segment tile (~96%)
#pragma unroll
      for (int i = 0; i < 16; ++i) {
        const float ei = __shfl(er[i & 3], (i >> 2) << 4, 64);
        den += ei;
        sum[0] += pf[i].x; sum[1] += pf[i].y; sum[2] += pf[i].z; sum[3] += pf[i].w;
        mx[0] = fmaxf(mx[0], pf[i].x); mx[1] = fmaxf(mx[1], pf[i].y);
        mx[2] = fmaxf(mx[2], pf[i].z); mx[3] = fmaxf(mx[3], pf[i].w);
        at[0] = fmaf(ei, pf[i].x, at[0]); at[1] = fmaf(ei, pf[i].y, at[1]);
        at[2] = fmaf(ei, pf[i].z, at[2]); at[3] = fmaf(ei, pf[i].w, at[3]);
      }
    } else {                            // boundary tile: per-row segment check
#pragma unroll
      for (int i = 0; i < 16; ++i) {
        const int sg = batch[r0t + i];  // uniform -> s_load
        if (sg != curseg) {
          FLUSH(curseg);
          RESET();
          curseg = sg;
        }
        const float ei = __shfl(er[i & 3], (i >> 2) << 4, 64);
        den += ei;
        sum[0] += pf[i].x; sum[1] += pf[i].y; sum[2] += pf[i].z; sum[3] += pf[i].w;
        mx[0] = fmaxf(mx[0], pf[i].x); mx[1] = fmaxf(mx[1], pf[i].y);
        mx[2] = fmaxf(mx[2], pf[i].z); mx[3] = fmaxf(mx[3], pf[i].w);
        at[0] = fmaf(ei, pf[i].x, at[0]); at[1] = fmaf(ei, pf[i].y, at[1]);
        at[2] = fmaf(ei, pf[i].w, at[3]) , at[2] = fmaf(ei, pf[i].z, at[2]);
      }
    }
  }
  if (curseg >= 0) FLUSH(curseg);
}

// ---------------------------------------------------------------------------
// Finalize + head: z = {sum/cnt, decode(max), attn/den}; y = z@wp+bp; LN.
// ---------------------------------------------------------------------------
__global__ __launch_bounds__(256) void head_ln(
    const float* __restrict__ gsum, const unsigned* __restrict__ gmx,
    const float* __restrict__ gat, const float* __restrict__ gden,
    const int* __restrict__ batch, const float* __restrict__ wp,
    const float* __restrict__ bp, const float* __restrict__ gam,
    const float* __restrict__ bet, float* __restrict__ out)
{
  const int g = blockIdx.x;
  const int tid = threadIdx.x;
  const int w = tid >> 6, lane = tid & 63;
  __shared__ int sb[2];
  __shared__ float z[768];
  __shared__ __align__(16) float part[4][256];
  __shared__ float red[256];

  if (tid < 2) sb[tid] = lower_bound_batch(batch, g + tid);
  __syncthreads();
  const float cnt = (float)(sb[1] - sb[0]);

  {
    const float s = gsum[(size_t)g * 256 + tid];
    const unsigned k = gmx[(size_t)g * 256 + tid];
    const unsigned u = (k & 0x80000000u) ? (k ^ 0x80000000u) : ~k;
    const float a = gat[(size_t)g * 256 + tid];
    const float den = gden[g];
    z[tid]       = (cnt > 0.f) ? s / cnt : 0.f;
    z[256 + tid] = (cnt > 0.f) ? __uint_as_float(u) : 0.f;
    z[512 + tid] = a / fmaxf(den, 1e-16f);
  }
  __syncthreads();

  f32x4 acc = (f32x4){0.f, 0.f, 0.f, 0.f};
  const float4* wp4 = (const float4*)wp;  // wp[k*256 + lane*4] = wp4[k*64 + lane]
  const int k0 = w * 192;
#pragma unroll 8
  for (int k = k0; k < k0 + 192; ++k) {
    float4 wv = wp4[(size_t)k * 64 + lane];
    float zk = z[k];
    acc[0] = fmaf(zk, wv.x, acc[0]);
    acc[1] = fmaf(zk, wv.y, acc[1]);
    acc[2] = fmaf(zk, wv.z, acc[2]);
    acc[3] = fmaf(zk, wv.w, acc[3]);
  }
  *(f32x4*)&part[w][lane * 4] = acc;
  __syncthreads();

  const int t = tid;
  float y = bp[t] + part[0][t] + part[1][t] + part[2][t] + part[3][t];

  red[t] = y;
  __syncthreads();
  for (int wd = 128; wd > 0; wd >>= 1) {
    if (t < wd) red[t] += red[t + wd];
    __syncthreads();
  }
  const float mu = red[0] * (1.f / 256.f);
  __syncthreads();
  float d = y - mu;
  red[t] = d * d;
  __syncthreads();
  for (int wd = 128; wd > 0; wd >>= 1) {
    if (t < wd) red[t] += red[t + wd];
    __syncthreads();
  }
  const float var = red[0] * (1.f / 256.f);
  const float is = rsqrtf(var + 1e-5f);
  out[(size_t)g * 256 + t] = fmaf(d * is, gam[t], bet[t]);
}

// ---------------------------------------------------------------------------
extern "C" void kernel_launch(void* const* d_in, const int* in_sizes, int n_in,
                              void* d_out, int out_size, void* d_ws, size_t ws_size,
                              hipStream_t stream) {
  const float* x   = (const float*)d_in[0];
  const int*   bat = (const int*)d_in[1];
  const float* w1  = (const float*)d_in[2];
  const float* b1  = (const float*)d_in[3];
  const float* w2  = (const float*)d_in[4];
  const float* b2  = (const float*)d_in[5];
  const float* wp  = (const float*)d_in[6];
  const float* bp  = (const float*)d_in[7];
  const float* gam = (const float*)d_in[8];
  const float* bet = (const float*)d_in[9];
  float* out = (float*)d_out;

  // ws: gsum[512*256] | gmx[512*256] | gat[512*256] | gden[512]
  float* gsum   = (float*)d_ws;
  unsigned* gmx = (unsigned*)(gsum + (size_t)NGRAPH * 256);
  float* gat    = (float*)(gmx + (size_t)NGRAPH * 256);
  float* gden   = gat + (size_t)NGRAPH * 256;
  const size_t zbytes = ((size_t)NGRAPH * 256 * 3 + NGRAPH) * 4;

  hipMemsetAsync(d_ws, 0, zbytes, stream);
  hipLaunchKernelGGL(fused_gate_pool, dim3(NBLK), dim3(256), 0, stream,
                     x, bat, w1, b1, w2, b2, gsum, gmx, gat, gden);
  hipLaunchKernelGGL(head_ln, dim3(NGRAPH), dim3(256), 0, stream,
                     gsum, gmx, gat, gden, bat, wp, bp, gam, bet, out);
}